// Round 6
// baseline (216.609 us; speedup 1.0000x reference)
//
#include <hip/hip_runtime.h>

#define NN 50000
#define NE 800000
#define NB 196          // ceil(50000/256) buckets (256 nodes each)
#define BCAP 4608       // fixed per-bucket capacity (mean 4096, sigma 64 -> +8 sigma)
#define KPAD 136        // 128 + 8 bf16 pad (16B-aligned rows)
#define WSLAB (2 * 64 * KPAD)   // ushorts per W slab (hi + lo)
#define CHUNKS 782      // ceil(50000/64)
#define G1A 391         // gemm1 chunks in k_fg1 (rest in k_bg1)
#define NBF 256         // bfill blocks
#define AGT 3125        // aggemm2 blocks: 16-node tiles (full occupancy: 12.2 blk/CU)
#define EWCAP 224       // per-wave (s,dis) cache entries (mean 64, sigma 8 -> +20 sigma)

typedef __bf16 bf16x8 __attribute__((ext_vector_type(8)));
typedef float  f32x4  __attribute__((ext_vector_type(4)));

static __device__ __forceinline__ float bf2f(unsigned short h){
  union { unsigned u; float f; } c; c.u = ((unsigned)h) << 16; return c.f;
}
static __device__ __forceinline__ unsigned short f2bf(float f){
  union { float f; unsigned u; } c; c.f = f;
  unsigned u = c.u;
  return (unsigned short)((u + 0x7fffu + ((u >> 16) & 1u)) >> 16);
}
static __device__ __forceinline__ void split8(const float* f, bf16x8& hi, bf16x8& lo){
  #pragma unroll
  for (int j = 0; j < 8; j++){
    __bf16 h = (__bf16)f[j];
    hi[j] = h;
    lo[j] = (__bf16)(f[j] - (float)h);
  }
}
// a[j] += s * bf16row[j]  (fmac: same VALU cost as plain add)
static __device__ __forceinline__ void addu4s(float* a, uint4 w, float s){
  a[0] = fmaf(s, bf2f((unsigned short)(w.x & 0xffffu)), a[0]);
  a[1] = fmaf(s, bf2f((unsigned short)(w.x >> 16)),     a[1]);
  a[2] = fmaf(s, bf2f((unsigned short)(w.y & 0xffffu)), a[2]);
  a[3] = fmaf(s, bf2f((unsigned short)(w.y >> 16)),     a[3]);
  a[4] = fmaf(s, bf2f((unsigned short)(w.z & 0xffffu)), a[4]);
  a[5] = fmaf(s, bf2f((unsigned short)(w.z >> 16)),     a[5]);
  a[6] = fmaf(s, bf2f((unsigned short)(w.w & 0xffffu)), a[6]);
  a[7] = fmaf(s, bf2f((unsigned short)(w.w >> 16)),     a[7]);
}

// Layer-1 GEMM body (UNSCALED output: y1u = bf16(x @ W1), no dis dependency).
static __device__ __forceinline__ void gemm1_body(int chunk, int t,
    const float* __restrict__ X, const unsigned short* __restrict__ wbuf,
    unsigned short* __restrict__ Y){
  const int wv = t >> 6;
  const int lane = t & 63;
  const int m = lane & 15;
  const int quad = lane >> 4;
  const int R0 = chunk * 64;
  const int row = R0 + wv * 16 + m;
  const int rowc = min(row, NN - 1);
  const float* pX = X + (size_t)rowc * 128 + quad * 8;

  f32x4 acc[8];
  #pragma unroll
  for (int tt = 0; tt < 8; tt++) acc[tt] = (f32x4){0.f, 0.f, 0.f, 0.f};

  #pragma unroll
  for (int ki = 0; ki < 4; ki++){
    float a[8];
    *(float4*)(a)     = *(const float4*)(pX + ki * 32);
    *(float4*)(a + 4) = *(const float4*)(pX + ki * 32 + 4);
    bf16x8 ah, al;
    split8(a, ah, al);
    #pragma unroll
    for (int tt = 0; tt < 8; tt++){
      const unsigned short* bp = wbuf + (tt >> 2) * WSLAB
                               + ((tt & 3) * 16 + m) * KPAD + ki * 32 + quad * 8;
      bf16x8 bh = *(const bf16x8*)bp;
      bf16x8 bl = *(const bf16x8*)(bp + 64 * KPAD);
      acc[tt] = __builtin_amdgcn_mfma_f32_16x16x32_bf16(ah, bh, acc[tt], 0, 0, 0);
      acc[tt] = __builtin_amdgcn_mfma_f32_16x16x32_bf16(ah, bl, acc[tt], 0, 0, 0);
      acc[tt] = __builtin_amdgcn_mfma_f32_16x16x32_bf16(al, bh, acc[tt], 0, 0, 0);
    }
  }

  const int orow = R0 + wv * 16 + quad * 4;
  #pragma unroll
  for (int r = 0; r < 4; r++){
    int gr = orow + r;
    if (gr < NN){
      #pragma unroll
      for (int tt = 0; tt < 8; tt++)
        Y[(size_t)gr * 128 + (tt >> 2) * 64 + (tt & 3) * 16 + m] = f2bf(acc[tt][r]);
    }
  }
}

// blocks 0..2: W -> per-slab [n][KPAD] hi/lo bf16. block 3: zero gcur.
__global__ __launch_bounds__(256) void k_prep(const float* __restrict__ W1,
    const float* __restrict__ W2, unsigned short* __restrict__ wbuf,
    int* __restrict__ gcur){
  int s = blockIdx.x;
  if (s == 3){
    if (threadIdx.x < NB) gcur[threadIdx.x] = 0;
    return;
  }
  const float* W = (s < 2) ? W1 : W2;
  int ldw = (s < 2) ? 128 : 64;
  int coff = (s == 1) ? 64 : 0;
  unsigned short* wh = wbuf + (size_t)s * WSLAB;
  unsigned short* wl = wh + 64 * KPAD;
  for (int i = threadIdx.x; i < 128 * 64; i += 256){
    int k = i >> 6, n = i & 63;
    float v = W[(size_t)k * ldw + coff + n];
    unsigned short h = f2bf(v);
    unsigned short l = f2bf(v - bf2f(h));
    wh[n * KPAD + k] = h;
    wl[n * KPAD + k] = l;
  }
}

// Heterogeneous: blocks 0..255 = two-pass bfill (R8, proven); 256..646 =
// gemm1 chunks 0..390 (independent of the CSR chain -> true pipe overlap).
__global__ __launch_bounds__(256) void k_fg1(const int* __restrict__ src,
    const int* __restrict__ dst, int* __restrict__ gcur, unsigned* __restrict__ stg,
    const float* __restrict__ X, const unsigned short* __restrict__ wbuf,
    unsigned short* __restrict__ Y){
  const int bid = blockIdx.x;
  const int t = threadIdx.x;
  if (bid >= NBF){
    gemm1_body(bid - NBF, t, X, wbuf, Y);
    return;
  }
  __shared__ int lcnt[NB];
  __shared__ int gbase[NB];
  for (int i = t; i < NB; i += 256) lcnt[i] = 0;
  __syncthreads();
  const int per = (NE + NBF - 1) / NBF;
  const int e0 = bid * per, e1 = min(e0 + per, NE);
  for (int e = e0 + t; e < e1; e += 256)
    atomicAdd(&lcnt[dst[e] >> 8], 1);
  __syncthreads();
  for (int b = t; b < NB; b += 256){
    gbase[b] = atomicAdd(&gcur[b], lcnt[b]);
    lcnt[b] = 0;
  }
  __syncthreads();
  for (int e = e0 + t; e < e1; e += 256){
    int d = dst[e];
    int b = d >> 8;
    unsigned entry = (unsigned)src[e] | (((unsigned)d & 255u) << 16);
    int pos = gbase[b] + atomicAdd(&lcnt[b], 1);
    if (pos < BCAP) stg[(size_t)b * BCAP + pos] = entry;
  }
}

// Heterogeneous: blocks 0..195 = per-bucket CSR build (R8); 196..586 =
// gemm1 chunks 391..781.
__global__ __launch_bounds__(256) void k_bg1(const unsigned* __restrict__ stg,
    const int* __restrict__ gcur, int* __restrict__ rowstart, int* __restrict__ cnt,
    float* __restrict__ dis, int* __restrict__ csr,
    const float* __restrict__ X, const unsigned short* __restrict__ wbuf,
    unsigned short* __restrict__ Y){
  const int bid = blockIdx.x;
  const int t = threadIdx.x;
  if (bid >= NB){
    gemm1_body(G1A + (bid - NB), t, X, wbuf, Y);
    return;
  }
  __shared__ int lcnt[256];
  __shared__ int sm[256];
  const int b = bid;
  const int ecnt = min(gcur[b], BCAP);
  const int ebase = b * BCAP;
  lcnt[t] = 0;
  __syncthreads();
  for (int i = t; i < ecnt; i += 256){
    unsigned en = stg[ebase + i];
    atomicAdd(&lcnt[(en >> 16) & 255u], 1);
  }
  __syncthreads();
  int v = lcnt[t];
  sm[t] = v;
  __syncthreads();
  #pragma unroll
  for (int off = 1; off < 256; off <<= 1){
    int x = (t >= off) ? sm[t - off] : 0;
    __syncthreads();
    sm[t] += x;
    __syncthreads();
  }
  const int loff = sm[t] - v;
  const int node = (b << 8) + t;
  if (node < NN){
    rowstart[node] = ebase + loff;
    cnt[node] = v;
    dis[node] = rsqrtf((float)v + 1.0f);
  }
  __syncthreads();
  lcnt[t] = loff;
  __syncthreads();
  for (int i = t; i < ecnt; i += 256){
    unsigned en = stg[ebase + i];
    int pos = atomicAdd(&lcnt[(en >> 16) & 255u], 1);
    csr[ebase + pos] = (int)(en & 0xffffu);
  }
}

// Per-node gather body: (s,d) from LDS ecache, row loads free-running.
// All array indices static; every arg a scalar register (rule #20 fix).
static __device__ __forceinline__ void gather_node(
    const unsigned short* __restrict__ Y, const uint2* __restrict__ ec,
    int eoff, int ce, int n, float dn, int q, int l, const float* bi,
    unsigned short* __restrict__ hrow){
  float a[8] = {0.f, 0.f, 0.f, 0.f, 0.f, 0.f, 0.f, 0.f};
  if (q == 0)   // self term: dn * u[n]
    addu4s(a, *(const uint4*)(Y + (size_t)n * 128 + (l << 3)), dn);
  #pragma unroll 1
  for (int i = 0; i < ce; i += 16){
    const int j0 = i + q, j1 = i + 4 + q, j2 = i + 8 + q, j3 = i + 12 + q;
    uint2 e0 = ec[eoff + (j0 < ce ? j0 : 0)];
    uint2 e1 = ec[eoff + (j1 < ce ? j1 : 0)];
    uint2 e2 = ec[eoff + (j2 < ce ? j2 : 0)];
    uint2 e3 = ec[eoff + (j3 < ce ? j3 : 0)];
    float d0 = j0 < ce ? __uint_as_float(e0.y) : 0.f;
    float d1 = j1 < ce ? __uint_as_float(e1.y) : 0.f;
    float d2 = j2 < ce ? __uint_as_float(e2.y) : 0.f;
    float d3 = j3 < ce ? __uint_as_float(e3.y) : 0.f;
    uint4 w0 = *(const uint4*)(Y + (size_t)e0.x * 128 + (l << 3));
    uint4 w1 = *(const uint4*)(Y + (size_t)e1.x * 128 + (l << 3));
    uint4 w2 = *(const uint4*)(Y + (size_t)e2.x * 128 + (l << 3));
    uint4 w3 = *(const uint4*)(Y + (size_t)e3.x * 128 + (l << 3));
    addu4s(a, w0, d0); addu4s(a, w1, d1); addu4s(a, w2, d2); addu4s(a, w3, d3);
  }
  #pragma unroll
  for (int j = 0; j < 8; j++){
    a[j] += __shfl_xor(a[j], 16);
    a[j] += __shfl_xor(a[j], 32);
  }
  if (q == 0){
    unsigned hv[4];
    #pragma unroll
    for (int j = 0; j < 4; j++){
      float o0 = fmaxf(dn * a[2 * j]     + bi[2 * j],     0.f);
      float o1 = fmaxf(dn * a[2 * j + 1] + bi[2 * j + 1], 0.f);
      hv[j] = (unsigned)f2bf(o0) | ((unsigned)f2bf(o1) << 16);
    }
    *(uint4*)(hrow + (l << 3)) = make_uint4(hv[0], hv[1], hv[2], hv[3]);
  }
}

// FUSED agg1 + gemm2, v6: wave-parallel (csr,dis) resolve into LDS,
// scratch-spill fixed. R5 post-mortem: rs[]/ct[]/dnv[] runtime-indexed in
// the unroll-1 node loop went to SCRATCH (WRITE_SIZE 6->49 MB!). v6 hoists
// the per-node body into gather_node() called 4x with named scalars, so
// every private index is compile-time (rule #20). Phase A unchanged: the
// wave's 4 consecutive nodes share one contiguous csr range; resolve all
// (s, dis[s]) in one parallel latency into LDS, so phase-B row loads have
// no in-flight address deps and pipeline across iterations and nodes.
__global__ __launch_bounds__(256, 8) void k_aggemm2(const unsigned short* __restrict__ Y,
    const int* __restrict__ rowstart, const int* __restrict__ cnt,
    const int* __restrict__ csr, const float* __restrict__ dis,
    const float* __restrict__ bias, const unsigned short* __restrict__ Wsl,
    unsigned short* __restrict__ Y2){
  __shared__ unsigned short hbuf[16 * KPAD];
  __shared__ uint2 ecache[4][EWCAP];
  const int t = threadIdx.x;
  const int wv = t >> 6;
  const int lane = t & 63;
  const int q = lane >> 4;
  const int l = lane & 15;
  const int R0 = blockIdx.x * 16;
  const int n_base = R0 + wv * 4;      // wave owns 4 consecutive nodes

  float bi[8];
  if (q == 0){
    *(float4*)(bi)     = *(const float4*)(bias + (l << 3));
    *(float4*)(bi + 4) = *(const float4*)(bias + (l << 3) + 4);
  }

  // ---- phase A: resolve (s, dis[s]) for the wave's contiguous csr range ----
  const int rs0 = rowstart[n_base];
  const int rs1 = rowstart[n_base + 1];
  const int rs2 = rowstart[n_base + 2];
  const int rs3 = rowstart[n_base + 3];
  const int ct0 = cnt[n_base];
  const int ct1 = cnt[n_base + 1];
  const int ct2 = cnt[n_base + 2];
  const int ct3 = cnt[n_base + 3];
  const float dn0 = dis[n_base];
  const float dn1 = dis[n_base + 1];
  const float dn2 = dis[n_base + 2];
  const float dn3 = dis[n_base + 3];
  int total = min((rs3 + ct3) - rs0, EWCAP);   // contiguous within bucket
  const uint2* ec = &ecache[wv][0];
  for (int e = lane; e < total; e += 64){
    int s = csr[rs0 + e];
    ecache[wv][e] = make_uint2((unsigned)s, __float_as_uint(dis[s]));
  }
  __syncthreads();   // ecache visibility

  // ---- phase B: 4 static calls, all private indices compile-time ----
  gather_node(Y, ec, rs0 - rs0, min(ct0, total),            n_base,     dn0, q, l, bi,
              hbuf + (wv * 4 + 0) * KPAD);
  gather_node(Y, ec, rs1 - rs0, min(ct1, total - (rs1-rs0)), n_base + 1, dn1, q, l, bi,
              hbuf + (wv * 4 + 1) * KPAD);
  gather_node(Y, ec, rs2 - rs0, min(ct2, total - (rs2-rs0)), n_base + 2, dn2, q, l, bi,
              hbuf + (wv * 4 + 2) * KPAD);
  gather_node(Y, ec, rs3 - rs0, min(ct3, total - (rs3-rs0)), n_base + 3, dn3, q, l, bi,
              hbuf + (wv * 4 + 3) * KPAD);
  __syncthreads();

  // ---- phase 2: 16-row gemm2 from LDS (A = single bf16 h; ah*(bh+bl)) ----
  // wave wv owns output cols [wv*16, wv*16+16); rows = the 16-node tile.
  const int m = l;
  const int quad = q;
  f32x4 acc = (f32x4){0.f, 0.f, 0.f, 0.f};

  #pragma unroll
  for (int ki = 0; ki < 4; ki++){
    bf16x8 ah = *(const bf16x8*)(hbuf + m * KPAD + ki * 32 + quad * 8);
    const unsigned short* bp = Wsl + (wv * 16 + m) * KPAD + ki * 32 + quad * 8;
    bf16x8 bh = *(const bf16x8*)bp;
    bf16x8 bl = *(const bf16x8*)(bp + 64 * KPAD);
    acc = __builtin_amdgcn_mfma_f32_16x16x32_bf16(ah, bh, acc, 0, 0, 0);
    acc = __builtin_amdgcn_mfma_f32_16x16x32_bf16(ah, bl, acc, 0, 0, 0);
  }

  const int orow = R0 + quad * 4;
  #pragma unroll
  for (int r = 0; r < 4; r++){
    int gr = orow + r;
    float dsc = dis[gr];
    Y2[(size_t)gr * 64 + wv * 16 + m] = f2bf(acc[r] * dsc);
  }
}

// Final aggregation D=64, eighth-wave edges; predicated single-width loop.
__global__ __launch_bounds__(256) void k_agg64(const unsigned short* __restrict__ Y,
    const int* __restrict__ rowstart, const int* __restrict__ cnt,
    const int* __restrict__ csr, const float* __restrict__ dis,
    const float* __restrict__ bias, float* __restrict__ OUT){
  const int n = (blockIdx.x * 256 + threadIdx.x) >> 6;
  const int lane = threadIdx.x & 63;
  const int g = lane >> 3;
  const int l = lane & 7;
  if (n >= NN) return;
  float a[8] = {0.f, 0.f, 0.f, 0.f, 0.f, 0.f, 0.f, 0.f};
  if (g == 0)
    addu4s(a, *(const uint4*)(Y + (size_t)n * 64 + (l << 3)), 1.f);
  const int start = rowstart[n];
  const int end = start + cnt[n];
  #pragma unroll 1
  for (int i = start; i < end; i += 16){
    const int i0 = i + g, i1 = i + 8 + g;
    const int c0 = i0 < end ? i0 : start;
    const int c1 = i1 < end ? i1 : start;
    int s0 = csr[c0], s1 = csr[c1];
    float d0 = i0 < end ? 1.f : 0.f;
    float d1 = i1 < end ? 1.f : 0.f;
    uint4 w0 = *(const uint4*)(Y + (size_t)s0 * 64 + (l << 3));
    uint4 w1 = *(const uint4*)(Y + (size_t)s1 * 64 + (l << 3));
    addu4s(a, w0, d0); addu4s(a, w1, d1);
  }
  #pragma unroll
  for (int j = 0; j < 8; j++){
    a[j] += __shfl_xor(a[j], 8);
    a[j] += __shfl_xor(a[j], 16);
    a[j] += __shfl_xor(a[j], 32);
  }
  if (g == 0){
    const float dn = dis[n];
    float bi[8];
    *(float4*)(bi)     = *(const float4*)(bias + (l << 3));
    *(float4*)(bi + 4) = *(const float4*)(bias + (l << 3) + 4);
    float4 o0, o1;
    o0.x = dn * a[0] + bi[0]; o0.y = dn * a[1] + bi[1];
    o0.z = dn * a[2] + bi[2]; o0.w = dn * a[3] + bi[3];
    o1.x = dn * a[4] + bi[4]; o1.y = dn * a[5] + bi[5];
    o1.z = dn * a[6] + bi[6]; o1.w = dn * a[7] + bi[7];
    *(float4*)(OUT + (size_t)n * 64 + (l << 3))     = o0;
    *(float4*)(OUT + (size_t)n * 64 + (l << 3) + 4) = o1;
  }
}

extern "C" void kernel_launch(void* const* d_in, const int* in_sizes, int n_in,
                              void* d_out, int out_size, void* d_ws, size_t ws_size,
                              hipStream_t stream) {
  const float* x  = (const float*)d_in[0];
  const int*   ei = (const int*)d_in[1];
  const int*   src = ei;
  const int*   dst = ei + NE;
  const float* W1 = (const float*)d_in[2];
  const float* b1 = (const float*)d_in[3];
  const float* W2 = (const float*)d_in[4];
  const float* b2 = (const float*)d_in[5];
  float* out = (float*)d_out;

  char* w = (char*)d_ws;
  auto alloc = [&](size_t bytes){ void* p = (void*)w; w += (bytes + 255) & ~(size_t)255; return p; };
  int*   gcur     = (int*)alloc(NB * 4);
  int*   rowstart = (int*)alloc((size_t)NN * 4);
  int*   cnt      = (int*)alloc((size_t)NN * 4);
  float* dis      = (float*)alloc((size_t)NN * 4);
  unsigned* stg   = (unsigned*)alloc((size_t)NB * BCAP * 4);
  int*   csr      = (int*)alloc((size_t)NB * BCAP * 4);
  unsigned short* y1 = (unsigned short*)alloc((size_t)NN * 128 * 2);
  unsigned short* y2 = (unsigned short*)alloc((size_t)NN * 64 * 2);
  unsigned short* wbuf = (unsigned short*)alloc((size_t)3 * WSLAB * 2);

  const int AGG_BLOCKS = (NN * 64 + 255) / 256;   // wave per node
  unsigned short* wsl2 = wbuf + (size_t)2 * WSLAB;

  k_prep<<<4, 256, 0, stream>>>(W1, W2, wbuf, gcur);
  k_fg1 <<<NBF + G1A, 256, 0, stream>>>(src, dst, gcur, stg, x, wbuf, y1);
  k_bg1 <<<NB + (CHUNKS - G1A), 256, 0, stream>>>(stg, gcur, rowstart, cnt, dis, csr,
                                                  x, wbuf, y1);
  k_aggemm2<<<AGT, 256, 0, stream>>>(y1, rowstart, cnt, csr, dis, b1, wsl2, y2);
  k_agg64<<<AGG_BLOCKS, 256, 0, stream>>>(y2, rowstart, cnt, csr, dis, b2, out);
}

// Round 7
// 190.280 us; speedup vs baseline: 1.1384x; 1.1384x over previous
//
#include <hip/hip_runtime.h>

#define NN 50000
#define NE 800000
#define NB 196          // ceil(50000/256) buckets (256 nodes each)
#define BCAP 4608       // fixed per-bucket capacity (mean 4096, sigma 64 -> +8 sigma)
#define KPAD 136        // 128 + 8 bf16 pad (16B-aligned rows)
#define WSLAB (2 * 64 * KPAD)   // ushorts per W slab (hi + lo)
#define CHUNKS 782      // ceil(50000/64)
#define G1A 391         // gemm1 chunks in k_fg1 (rest in k_bg1)
#define NBF 256         // bfill blocks
#define AGT 3125        // aggemm2 blocks: 16-node tiles
#define EWCAP 224       // per-wave (s,dis) cache entries (mean 64, sigma 8 -> +20 sigma)

typedef __bf16 bf16x8 __attribute__((ext_vector_type(8)));
typedef float  f32x4  __attribute__((ext_vector_type(4)));

static __device__ __forceinline__ float bf2f(unsigned short h){
  union { unsigned u; float f; } c; c.u = ((unsigned)h) << 16; return c.f;
}
static __device__ __forceinline__ unsigned short f2bf(float f){
  union { float f; unsigned u; } c; c.f = f;
  unsigned u = c.u;
  return (unsigned short)((u + 0x7fffu + ((u >> 16) & 1u)) >> 16);
}
static __device__ __forceinline__ void split8(const float* f, bf16x8& hi, bf16x8& lo){
  #pragma unroll
  for (int j = 0; j < 8; j++){
    __bf16 h = (__bf16)f[j];
    hi[j] = h;
    lo[j] = (__bf16)(f[j] - (float)h);
  }
}
// a[j] += s * bf16row[j]  (fmac: same VALU cost as plain add)
static __device__ __forceinline__ void addu4s(float* a, uint4 w, float s){
  a[0] = fmaf(s, bf2f((unsigned short)(w.x & 0xffffu)), a[0]);
  a[1] = fmaf(s, bf2f((unsigned short)(w.x >> 16)),     a[1]);
  a[2] = fmaf(s, bf2f((unsigned short)(w.y & 0xffffu)), a[2]);
  a[3] = fmaf(s, bf2f((unsigned short)(w.y >> 16)),     a[3]);
  a[4] = fmaf(s, bf2f((unsigned short)(w.z & 0xffffu)), a[4]);
  a[5] = fmaf(s, bf2f((unsigned short)(w.z >> 16)),     a[5]);
  a[6] = fmaf(s, bf2f((unsigned short)(w.w & 0xffffu)), a[6]);
  a[7] = fmaf(s, bf2f((unsigned short)(w.w >> 16)),     a[7]);
}

// Layer-1 GEMM body (UNSCALED output: y1u = bf16(x @ W1), no dis dependency).
static __device__ __forceinline__ void gemm1_body(int chunk, int t,
    const float* __restrict__ X, const unsigned short* __restrict__ wbuf,
    unsigned short* __restrict__ Y){
  const int wv = t >> 6;
  const int lane = t & 63;
  const int m = lane & 15;
  const int quad = lane >> 4;
  const int R0 = chunk * 64;
  const int row = R0 + wv * 16 + m;
  const int rowc = min(row, NN - 1);
  const float* pX = X + (size_t)rowc * 128 + quad * 8;

  f32x4 acc[8];
  #pragma unroll
  for (int tt = 0; tt < 8; tt++) acc[tt] = (f32x4){0.f, 0.f, 0.f, 0.f};

  #pragma unroll
  for (int ki = 0; ki < 4; ki++){
    float a[8];
    *(float4*)(a)     = *(const float4*)(pX + ki * 32);
    *(float4*)(a + 4) = *(const float4*)(pX + ki * 32 + 4);
    bf16x8 ah, al;
    split8(a, ah, al);
    #pragma unroll
    for (int tt = 0; tt < 8; tt++){
      const unsigned short* bp = wbuf + (tt >> 2) * WSLAB
                               + ((tt & 3) * 16 + m) * KPAD + ki * 32 + quad * 8;
      bf16x8 bh = *(const bf16x8*)bp;
      bf16x8 bl = *(const bf16x8*)(bp + 64 * KPAD);
      acc[tt] = __builtin_amdgcn_mfma_f32_16x16x32_bf16(ah, bh, acc[tt], 0, 0, 0);
      acc[tt] = __builtin_amdgcn_mfma_f32_16x16x32_bf16(ah, bl, acc[tt], 0, 0, 0);
      acc[tt] = __builtin_amdgcn_mfma_f32_16x16x32_bf16(al, bh, acc[tt], 0, 0, 0);
    }
  }

  const int orow = R0 + wv * 16 + quad * 4;
  #pragma unroll
  for (int r = 0; r < 4; r++){
    int gr = orow + r;
    if (gr < NN){
      #pragma unroll
      for (int tt = 0; tt < 8; tt++)
        Y[(size_t)gr * 128 + (tt >> 2) * 64 + (tt & 3) * 16 + m] = f2bf(acc[tt][r]);
    }
  }
}

// blocks 0..2: W -> per-slab [n][KPAD] hi/lo bf16. block 3: zero gcur.
__global__ __launch_bounds__(256) void k_prep(const float* __restrict__ W1,
    const float* __restrict__ W2, unsigned short* __restrict__ wbuf,
    int* __restrict__ gcur){
  int s = blockIdx.x;
  if (s == 3){
    if (threadIdx.x < NB) gcur[threadIdx.x] = 0;
    return;
  }
  const float* W = (s < 2) ? W1 : W2;
  int ldw = (s < 2) ? 128 : 64;
  int coff = (s == 1) ? 64 : 0;
  unsigned short* wh = wbuf + (size_t)s * WSLAB;
  unsigned short* wl = wh + 64 * KPAD;
  for (int i = threadIdx.x; i < 128 * 64; i += 256){
    int k = i >> 6, n = i & 63;
    float v = W[(size_t)k * ldw + coff + n];
    unsigned short h = f2bf(v);
    unsigned short l = f2bf(v - bf2f(h));
    wh[n * KPAD + k] = h;
    wl[n * KPAD + k] = l;
  }
}

// Heterogeneous: blocks 0..255 = two-pass bfill (R8, proven); 256..646 =
// gemm1 chunks 0..390 (independent of the CSR chain -> true pipe overlap).
__global__ __launch_bounds__(256) void k_fg1(const int* __restrict__ src,
    const int* __restrict__ dst, int* __restrict__ gcur, unsigned* __restrict__ stg,
    const float* __restrict__ X, const unsigned short* __restrict__ wbuf,
    unsigned short* __restrict__ Y){
  const int bid = blockIdx.x;
  const int t = threadIdx.x;
  if (bid >= NBF){
    gemm1_body(bid - NBF, t, X, wbuf, Y);
    return;
  }
  __shared__ int lcnt[NB];
  __shared__ int gbase[NB];
  for (int i = t; i < NB; i += 256) lcnt[i] = 0;
  __syncthreads();
  const int per = (NE + NBF - 1) / NBF;
  const int e0 = bid * per, e1 = min(e0 + per, NE);
  for (int e = e0 + t; e < e1; e += 256)
    atomicAdd(&lcnt[dst[e] >> 8], 1);
  __syncthreads();
  for (int b = t; b < NB; b += 256){
    gbase[b] = atomicAdd(&gcur[b], lcnt[b]);
    lcnt[b] = 0;
  }
  __syncthreads();
  for (int e = e0 + t; e < e1; e += 256){
    int d = dst[e];
    int b = d >> 8;
    unsigned entry = (unsigned)src[e] | (((unsigned)d & 255u) << 16);
    int pos = gbase[b] + atomicAdd(&lcnt[b], 1);
    if (pos < BCAP) stg[(size_t)b * BCAP + pos] = entry;
  }
}

// Heterogeneous: blocks 0..195 = per-bucket CSR build (R8); 196..586 =
// gemm1 chunks 391..781.
__global__ __launch_bounds__(256) void k_bg1(const unsigned* __restrict__ stg,
    const int* __restrict__ gcur, int* __restrict__ rowstart, int* __restrict__ cnt,
    float* __restrict__ dis, int* __restrict__ csr,
    const float* __restrict__ X, const unsigned short* __restrict__ wbuf,
    unsigned short* __restrict__ Y){
  const int bid = blockIdx.x;
  const int t = threadIdx.x;
  if (bid >= NB){
    gemm1_body(G1A + (bid - NB), t, X, wbuf, Y);
    return;
  }
  __shared__ int lcnt[256];
  __shared__ int sm[256];
  const int b = bid;
  const int ecnt = min(gcur[b], BCAP);
  const int ebase = b * BCAP;
  lcnt[t] = 0;
  __syncthreads();
  for (int i = t; i < ecnt; i += 256){
    unsigned en = stg[ebase + i];
    atomicAdd(&lcnt[(en >> 16) & 255u], 1);
  }
  __syncthreads();
  int v = lcnt[t];
  sm[t] = v;
  __syncthreads();
  #pragma unroll
  for (int off = 1; off < 256; off <<= 1){
    int x = (t >= off) ? sm[t - off] : 0;
    __syncthreads();
    sm[t] += x;
    __syncthreads();
  }
  const int loff = sm[t] - v;
  const int node = (b << 8) + t;
  if (node < NN){
    rowstart[node] = ebase + loff;
    cnt[node] = v;
    dis[node] = rsqrtf((float)v + 1.0f);
  }
  __syncthreads();
  lcnt[t] = loff;
  __syncthreads();
  for (int i = t; i < ecnt; i += 256){
    unsigned en = stg[ebase + i];
    int pos = atomicAdd(&lcnt[(en >> 16) & 255u], 1);
    csr[ebase + pos] = (int)(en & 0xffffu);
  }
}

// Per-node gather body: (s,d) from LDS ecache, row loads free-running.
// All private array indices compile-time static.
static __device__ __forceinline__ void gather_node(
    const unsigned short* __restrict__ Y, const uint2* __restrict__ ec,
    int eoff, int ce, int n, float dn, int q, int l, const float* bi,
    unsigned short* __restrict__ hrow){
  float a[8] = {0.f, 0.f, 0.f, 0.f, 0.f, 0.f, 0.f, 0.f};
  if (q == 0)   // self term: dn * u[n]
    addu4s(a, *(const uint4*)(Y + (size_t)n * 128 + (l << 3)), dn);
  #pragma unroll 1
  for (int i = 0; i < ce; i += 16){
    const int j0 = i + q, j1 = i + 4 + q, j2 = i + 8 + q, j3 = i + 12 + q;
    uint2 e0 = ec[eoff + (j0 < ce ? j0 : 0)];
    uint2 e1 = ec[eoff + (j1 < ce ? j1 : 0)];
    uint2 e2 = ec[eoff + (j2 < ce ? j2 : 0)];
    uint2 e3 = ec[eoff + (j3 < ce ? j3 : 0)];
    float d0 = j0 < ce ? __uint_as_float(e0.y) : 0.f;
    float d1 = j1 < ce ? __uint_as_float(e1.y) : 0.f;
    float d2 = j2 < ce ? __uint_as_float(e2.y) : 0.f;
    float d3 = j3 < ce ? __uint_as_float(e3.y) : 0.f;
    uint4 w0 = *(const uint4*)(Y + (size_t)e0.x * 128 + (l << 3));
    uint4 w1 = *(const uint4*)(Y + (size_t)e1.x * 128 + (l << 3));
    uint4 w2 = *(const uint4*)(Y + (size_t)e2.x * 128 + (l << 3));
    uint4 w3 = *(const uint4*)(Y + (size_t)e3.x * 128 + (l << 3));
    addu4s(a, w0, d0); addu4s(a, w1, d1); addu4s(a, w2, d2); addu4s(a, w3, d3);
  }
  #pragma unroll
  for (int j = 0; j < 8; j++){
    a[j] += __shfl_xor(a[j], 16);
    a[j] += __shfl_xor(a[j], 32);
  }
  if (q == 0){
    unsigned hv[4];
    #pragma unroll
    for (int j = 0; j < 4; j++){
      float o0 = fmaxf(dn * a[2 * j]     + bi[2 * j],     0.f);
      float o1 = fmaxf(dn * a[2 * j + 1] + bi[2 * j + 1], 0.f);
      hv[j] = (unsigned)f2bf(o0) | ((unsigned)f2bf(o1) << 16);
    }
    *(uint4*)(hrow + (l << 3)) = make_uint4(hv[0], hv[1], hv[2], hv[3]);
  }
}

// FUSED agg1 + gemm2, v7: v6 minus the VGPR-capping launch_bounds.
// R6 post-mortem: __launch_bounds__(256, 8) (added in R5) forced VGPR=32,
// below the gather working set (4 in-flight uint4 rows + 8 acc + addrs)
// -> register SPILL to scratch = the 50-62 MB phantom WRITE_SIZE in R5/R6.
// Natural allocation (R4: 36 VGPR) never spilled and still permits the full
// 8 waves/SIMD (cap is 64 VGPR). Phase A (wave-cooperative csr/dis resolve
// into LDS) is otherwise unchanged -- this round cleanly measures it.
__global__ __launch_bounds__(256) void k_aggemm2(const unsigned short* __restrict__ Y,
    const int* __restrict__ rowstart, const int* __restrict__ cnt,
    const int* __restrict__ csr, const float* __restrict__ dis,
    const float* __restrict__ bias, const unsigned short* __restrict__ Wsl,
    unsigned short* __restrict__ Y2){
  __shared__ unsigned short hbuf[16 * KPAD];
  __shared__ uint2 ecache[4][EWCAP];
  const int t = threadIdx.x;
  const int wv = t >> 6;
  const int lane = t & 63;
  const int q = lane >> 4;
  const int l = lane & 15;
  const int R0 = blockIdx.x * 16;
  const int n_base = R0 + wv * 4;      // wave owns 4 consecutive nodes

  float bi[8];
  if (q == 0){
    *(float4*)(bi)     = *(const float4*)(bias + (l << 3));
    *(float4*)(bi + 4) = *(const float4*)(bias + (l << 3) + 4);
  }

  // ---- phase A: resolve (s, dis[s]) for the wave's contiguous csr range ----
  const int rs0 = rowstart[n_base];
  const int rs1 = rowstart[n_base + 1];
  const int rs2 = rowstart[n_base + 2];
  const int rs3 = rowstart[n_base + 3];
  const int ct0 = cnt[n_base];
  const int ct1 = cnt[n_base + 1];
  const int ct2 = cnt[n_base + 2];
  const int ct3 = cnt[n_base + 3];
  const float dn0 = dis[n_base];
  const float dn1 = dis[n_base + 1];
  const float dn2 = dis[n_base + 2];
  const float dn3 = dis[n_base + 3];
  int total = min((rs3 + ct3) - rs0, EWCAP);   // contiguous within bucket
  const uint2* ec = &ecache[wv][0];
  for (int e = lane; e < total; e += 64){
    int s = csr[rs0 + e];
    ecache[wv][e] = make_uint2((unsigned)s, __float_as_uint(dis[s]));
  }
  __syncthreads();   // ecache visibility

  // ---- phase B: 4 static calls, all private indices compile-time ----
  gather_node(Y, ec, rs0 - rs0, min(ct0, total),            n_base,     dn0, q, l, bi,
              hbuf + (wv * 4 + 0) * KPAD);
  gather_node(Y, ec, rs1 - rs0, min(ct1, total - (rs1-rs0)), n_base + 1, dn1, q, l, bi,
              hbuf + (wv * 4 + 1) * KPAD);
  gather_node(Y, ec, rs2 - rs0, min(ct2, total - (rs2-rs0)), n_base + 2, dn2, q, l, bi,
              hbuf + (wv * 4 + 2) * KPAD);
  gather_node(Y, ec, rs3 - rs0, min(ct3, total - (rs3-rs0)), n_base + 3, dn3, q, l, bi,
              hbuf + (wv * 4 + 3) * KPAD);
  __syncthreads();

  // ---- phase 2: 16-row gemm2 from LDS (A = single bf16 h; ah*(bh+bl)) ----
  // wave wv owns output cols [wv*16, wv*16+16); rows = the 16-node tile.
  const int m = l;
  const int quad = q;
  f32x4 acc = (f32x4){0.f, 0.f, 0.f, 0.f};

  #pragma unroll
  for (int ki = 0; ki < 4; ki++){
    bf16x8 ah = *(const bf16x8*)(hbuf + m * KPAD + ki * 32 + quad * 8);
    const unsigned short* bp = Wsl + (wv * 16 + m) * KPAD + ki * 32 + quad * 8;
    bf16x8 bh = *(const bf16x8*)bp;
    bf16x8 bl = *(const bf16x8*)(bp + 64 * KPAD);
    acc = __builtin_amdgcn_mfma_f32_16x16x32_bf16(ah, bh, acc, 0, 0, 0);
    acc = __builtin_amdgcn_mfma_f32_16x16x32_bf16(ah, bl, acc, 0, 0, 0);
  }

  const int orow = R0 + quad * 4;
  #pragma unroll
  for (int r = 0; r < 4; r++){
    int gr = orow + r;
    float dsc = dis[gr];
    Y2[(size_t)gr * 64 + wv * 16 + m] = f2bf(acc[r] * dsc);
  }
}

// Final aggregation D=64, eighth-wave edges; predicated single-width loop.
__global__ __launch_bounds__(256) void k_agg64(const unsigned short* __restrict__ Y,
    const int* __restrict__ rowstart, const int* __restrict__ cnt,
    const int* __restrict__ csr, const float* __restrict__ dis,
    const float* __restrict__ bias, float* __restrict__ OUT){
  const int n = (blockIdx.x * 256 + threadIdx.x) >> 6;
  const int lane = threadIdx.x & 63;
  const int g = lane >> 3;
  const int l = lane & 7;
  if (n >= NN) return;
  float a[8] = {0.f, 0.f, 0.f, 0.f, 0.f, 0.f, 0.f, 0.f};
  if (g == 0)
    addu4s(a, *(const uint4*)(Y + (size_t)n * 64 + (l << 3)), 1.f);
  const int start = rowstart[n];
  const int end = start + cnt[n];
  #pragma unroll 1
  for (int i = start; i < end; i += 16){
    const int i0 = i + g, i1 = i + 8 + g;
    const int c0 = i0 < end ? i0 : start;
    const int c1 = i1 < end ? i1 : start;
    int s0 = csr[c0], s1 = csr[c1];
    float d0 = i0 < end ? 1.f : 0.f;
    float d1 = i1 < end ? 1.f : 0.f;
    uint4 w0 = *(const uint4*)(Y + (size_t)s0 * 64 + (l << 3));
    uint4 w1 = *(const uint4*)(Y + (size_t)s1 * 64 + (l << 3));
    addu4s(a, w0, d0); addu4s(a, w1, d1);
  }
  #pragma unroll
  for (int j = 0; j < 8; j++){
    a[j] += __shfl_xor(a[j], 8);
    a[j] += __shfl_xor(a[j], 16);
    a[j] += __shfl_xor(a[j], 32);
  }
  if (g == 0){
    const float dn = dis[n];
    float bi[8];
    *(float4*)(bi)     = *(const float4*)(bias + (l << 3));
    *(float4*)(bi + 4) = *(const float4*)(bias + (l << 3) + 4);
    float4 o0, o1;
    o0.x = dn * a[0] + bi[0]; o0.y = dn * a[1] + bi[1];
    o0.z = dn * a[2] + bi[2]; o0.w = dn * a[3] + bi[3];
    o1.x = dn * a[4] + bi[4]; o1.y = dn * a[5] + bi[5];
    o1.z = dn * a[6] + bi[6]; o1.w = dn * a[7] + bi[7];
    *(float4*)(OUT + (size_t)n * 64 + (l << 3))     = o0;
    *(float4*)(OUT + (size_t)n * 64 + (l << 3) + 4) = o1;
  }
}

extern "C" void kernel_launch(void* const* d_in, const int* in_sizes, int n_in,
                              void* d_out, int out_size, void* d_ws, size_t ws_size,
                              hipStream_t stream) {
  const float* x  = (const float*)d_in[0];
  const int*   ei = (const int*)d_in[1];
  const int*   src = ei;
  const int*   dst = ei + NE;
  const float* W1 = (const float*)d_in[2];
  const float* b1 = (const float*)d_in[3];
  const float* W2 = (const float*)d_in[4];
  const float* b2 = (const float*)d_in[5];
  float* out = (float*)d_out;

  char* w = (char*)d_ws;
  auto alloc = [&](size_t bytes){ void* p = (void*)w; w += (bytes + 255) & ~(size_t)255; return p; };
  int*   gcur     = (int*)alloc(NB * 4);
  int*   rowstart = (int*)alloc((size_t)NN * 4);
  int*   cnt      = (int*)alloc((size_t)NN * 4);
  float* dis      = (float*)alloc((size_t)NN * 4);
  unsigned* stg   = (unsigned*)alloc((size_t)NB * BCAP * 4);
  int*   csr      = (int*)alloc((size_t)NB * BCAP * 4);
  unsigned short* y1 = (unsigned short*)alloc((size_t)NN * 128 * 2);
  unsigned short* y2 = (unsigned short*)alloc((size_t)NN * 64 * 2);
  unsigned short* wbuf = (unsigned short*)alloc((size_t)3 * WSLAB * 2);

  const int AGG_BLOCKS = (NN * 64 + 255) / 256;   // wave per node
  unsigned short* wsl2 = wbuf + (size_t)2 * WSLAB;

  k_prep<<<4, 256, 0, stream>>>(W1, W2, wbuf, gcur);
  k_fg1 <<<NBF + G1A, 256, 0, stream>>>(src, dst, gcur, stg, x, wbuf, y1);
  k_bg1 <<<NB + (CHUNKS - G1A), 256, 0, stream>>>(stg, gcur, rowstart, cnt, dis, csr,
                                                  x, wbuf, y1);
  k_aggemm2<<<AGT, 256, 0, stream>>>(y1, rowstart, cnt, csr, dis, b1, wsl2, y2);
  k_agg64<<<AGG_BLOCKS, 256, 0, stream>>>(y2, rowstart, cnt, csr, dis, b2, out);
}